// Round 1
// baseline (529.730 us; speedup 1.0000x reference)
//
#include <hip/hip_runtime.h>
#include <math.h>

#define N 512
#define H 128
#define L 4
#define NUM_RBF 50
#define NMOL 16
#define NCHUNK 4
#define CHUNK (N / NCHUNK)   // 128
#define WIN 13               // RBF window width (width=0.1, spacing≈0.102 -> 13 covers all terms > 1e-8)

__device__ __forceinline__ float silu_f(float v) {
    return v / (1.0f + __expf(-v));
}

// x[i,h] = embed[clip(an[i],0,99), h]
__global__ __launch_bounds__(H) void k_embed(const int* __restrict__ an,
                                             const float* __restrict__ embed,
                                             float* __restrict__ x) {
    int i = blockIdx.x, h = threadIdx.x;
    int z = an[i];
    z = min(max(z, 0), 99);
    x[i * H + h] = embed[z * H + h];
}

// a[i,h] = b1[h] + sum_k x[i,k] * Wx[k,h]   (Wx = msg_w1[l, :H])
__global__ __launch_bounds__(H) void k_lin_a(const float* __restrict__ x,
                                             const float* __restrict__ wx,
                                             const float* __restrict__ b1,
                                             float* __restrict__ a) {
    __shared__ float xs[H];
    int i = blockIdx.x, h = threadIdx.x;
    xs[h] = x[i * H + h];
    __syncthreads();
    float acc = b1[h];
#pragma unroll 8
    for (int k = 0; k < H; k++) acc += xs[k] * wx[k * H + h];
    a[i * H + h] = acc;
}

// s_part[chunk,j,h] = sum_{i in chunk} valid(i,j) * silu(a[i,h] + rbf(d_ij)@Wr[:,h] + dir_ij@Wd[:,h])
// cnt_part[chunk,j] = number of valid i in chunk
// wfeat points at msg_w1[l] rows 128..180 (50 RBF rows + 3 dir rows), row stride H.
__global__ __launch_bounds__(H) void k_msg(const float* __restrict__ a,
                                           const float* __restrict__ pos,
                                           const float* __restrict__ wfeat,
                                           float* __restrict__ s_part,
                                           int* __restrict__ cnt_part) {
    int bid = blockIdx.x;
    int j = bid >> 2;       // NCHUNK == 4
    int chunk = bid & 3;
    int h = threadIdx.x;

    __shared__ float Wl[53 * H];     // 50 RBF rows + 3 dir rows
    __shared__ float feat[4][16];    // per staged i: 13 rbf + 3 dir components
    __shared__ int   k0s[4];
    __shared__ int   vals[4];

    for (int r = h; r < 53 * H; r += H) Wl[r] = wfeat[r];
    __syncthreads();

    float pjx = pos[j * 3 + 0], pjy = pos[j * 3 + 1], pjz = pos[j * 3 + 2];

    const float DELTA = 5.0f / 49.0f;
    const float INVD  = 49.0f / 5.0f;

    float acc = 0.0f;
    int cnt = 0;

    for (int ii0 = 0; ii0 < CHUNK; ii0 += 4) {
        int iBase = chunk * CHUNK + ii0;
        if (h < 64) {
            int ii = h >> 4, ln = h & 15;
            int i = iBase + ii;
            float dx = pos[i * 3 + 0] - pjx;
            float dy = pos[i * 3 + 1] - pjy;
            float dz = pos[i * 3 + 2] - pjz;
            float d = sqrtf(dx * dx + dy * dy + dz * dz);
            int v = (d < 5.0f) && (i != j);
            float rinv = 1.0f / fmaxf(d, 1e-8f);
            int k0 = (int)(d * INVD) - 6;
            k0 = max(0, min(k0, NUM_RBF - WIN));
            if (ln == 0) { k0s[ii] = k0; vals[ii] = v; }
            if (ln < WIN) {
                float t = d - (float)(k0 + ln) * DELTA;
                feat[ii][ln] = __expf(-t * t * 50.0f);   // 1/(2*0.1^2) = 50
            } else if (ln < 16) {
                float comp = (ln == 13) ? dx : ((ln == 14) ? dy : dz);
                feat[ii][ln] = comp * rinv;
            }
        }
        __syncthreads();
#pragma unroll
        for (int ii = 0; ii < 4; ii++) {
            if (vals[ii]) {                 // wave-uniform branch
                int i = iBase + ii;
                float p = a[i * H + h];
                int k0 = k0s[ii];
                const float* wrow = &Wl[k0 * H + h];
#pragma unroll
                for (int t = 0; t < WIN; t++) p += feat[ii][t] * wrow[t * H];
#pragma unroll
                for (int t = 0; t < 3; t++)  p += feat[ii][WIN + t] * Wl[(50 + t) * H + h];
                acc += silu_f(p);
                cnt++;
            }
        }
        __syncthreads();
    }

    s_part[(chunk * N + j) * H + h] = acc;
    if (h == 0) cnt_part[chunk * N + j] = cnt;
}

// aggr[j,h] = sum_k s[j,k]*W2[k,h] + cnt[j]*b2[h];
// hid = silu([x[j], aggr] @ U1 + ub1); x[j] += hid @ U2 + ub2
__global__ __launch_bounds__(H) void k_update(const float* __restrict__ s_part,
                                              const int* __restrict__ cnt_part,
                                              const float* __restrict__ w2,
                                              const float* __restrict__ b2,
                                              const float* __restrict__ u1,
                                              const float* __restrict__ ub1,
                                              const float* __restrict__ u2,
                                              const float* __restrict__ ub2,
                                              float* __restrict__ x) {
    int j = blockIdx.x, h = threadIdx.x;
    __shared__ float sj[H];
    __shared__ float xj[H];
    __shared__ float ag[H];
    __shared__ float hid[H];

    float s = 0.0f;
    for (int c = 0; c < NCHUNK; c++) s += s_part[(c * N + j) * H + h];
    sj[h] = s;
    xj[h] = x[j * H + h];
    int cnt = 0;
    for (int c = 0; c < NCHUNK; c++) cnt += cnt_part[c * N + j];
    __syncthreads();

    float aggr = (float)cnt * b2[h];
#pragma unroll 8
    for (int k = 0; k < H; k++) aggr += sj[k] * w2[k * H + h];
    ag[h] = aggr;
    __syncthreads();

    float pre = ub1[h];
#pragma unroll 8
    for (int k = 0; k < H; k++) pre += xj[k] * u1[k * H + h];
#pragma unroll 8
    for (int k = 0; k < H; k++) pre += ag[k] * u1[(H + k) * H + h];
    hid[h] = silu_f(pre);
    __syncthreads();

    float o = ub2[h];
#pragma unroll 8
    for (int k = 0; k < H; k++) o += hid[k] * u2[k * H + h];
    x[j * H + h] = xj[h] + o;
}

// per-molecule mean pool + 2-layer output MLP
__global__ __launch_bounds__(H) void k_pool(const float* __restrict__ x,
                                            const int* __restrict__ batch,
                                            const float* __restrict__ ow1,
                                            const float* __restrict__ ob1,
                                            const float* __restrict__ ow2,
                                            const float* __restrict__ ob2,
                                            float* __restrict__ out) {
    int m = blockIdx.x, h = threadIdx.x;
    __shared__ float pooled[H];
    __shared__ float hid[H / 2];

    float s = 0.0f;
    int cnt = 0;
    for (int i = 0; i < N; i++) {
        if (batch[i] == m) { s += x[i * H + h]; cnt++; }
    }
    pooled[h] = s / (float)max(cnt, 1);
    __syncthreads();

    if (h < H / 2) {
        float p = ob1[h];
        for (int k = 0; k < H; k++) p += pooled[k] * ow1[k * (H / 2) + h];
        hid[h] = silu_f(p);
    }
    __syncthreads();

    if (h == 0) {
        float o = ob2[0];
        for (int k = 0; k < H / 2; k++) o += hid[k] * ow2[k];
        out[m] = o;
    }
}

extern "C" void kernel_launch(void* const* d_in, const int* in_sizes, int n_in,
                              void* d_out, int out_size, void* d_ws, size_t ws_size,
                              hipStream_t stream) {
    const int*   an      = (const int*)d_in[0];
    const float* pos     = (const float*)d_in[1];
    const int*   batch   = (const int*)d_in[2];
    const float* embed   = (const float*)d_in[3];
    const float* msg_w1  = (const float*)d_in[4];   // L x 181 x 128
    const float* msg_b1  = (const float*)d_in[5];   // L x 128
    const float* msg_w2  = (const float*)d_in[6];   // L x 128 x 128
    const float* msg_b2  = (const float*)d_in[7];   // L x 128
    const float* upd_w1  = (const float*)d_in[8];   // L x 256 x 128
    const float* upd_b1  = (const float*)d_in[9];   // L x 128
    const float* upd_w2  = (const float*)d_in[10];  // L x 128 x 128
    const float* upd_b2  = (const float*)d_in[11];  // L x 128
    const float* out_w1  = (const float*)d_in[12];  // 128 x 64
    const float* out_b1  = (const float*)d_in[13];  // 64
    const float* out_w2  = (const float*)d_in[14];  // 64 x 1
    const float* out_b2  = (const float*)d_in[15];  // 1
    float* out = (float*)d_out;

    float* x      = (float*)d_ws;                    // N*H
    float* a      = x + N * H;                       // N*H
    float* s_part = a + N * H;                       // NCHUNK*N*H
    int*   cnt_p  = (int*)(s_part + NCHUNK * N * H); // NCHUNK*N

    k_embed<<<N, H, 0, stream>>>(an, embed, x);
    const int W1ROWS = H + NUM_RBF + 3;  // 181
    for (int l = 0; l < L; l++) {
        k_lin_a<<<N, H, 0, stream>>>(x, msg_w1 + l * W1ROWS * H, msg_b1 + l * H, a);
        k_msg<<<N * NCHUNK, H, 0, stream>>>(a, pos, msg_w1 + l * W1ROWS * H + H * H,
                                            s_part, cnt_p);
        k_update<<<N, H, 0, stream>>>(s_part, cnt_p,
                                      msg_w2 + l * H * H, msg_b2 + l * H,
                                      upd_w1 + l * 2 * H * H, upd_b1 + l * H,
                                      upd_w2 + l * H * H, upd_b2 + l * H, x);
    }
    k_pool<<<NMOL, H, 0, stream>>>(x, batch, out_w1, out_b1, out_w2, out_b2, out);
}

// Round 2
// 335.619 us; speedup vs baseline: 1.5784x; 1.5784x over previous
//
#include <hip/hip_runtime.h>
#include <math.h>

#define N 512
#define H 128
#define L 4
#define NUM_RBF 50
#define NMOL 16
#define SUPER 64          // i's staged per super-tile in k_msg
#define FSTRIDE 72        // bf16 row stride for F_lds (64 + 8 pad)

typedef __attribute__((ext_vector_type(8))) short short8;
typedef __attribute__((ext_vector_type(4))) float float4v;

__device__ __forceinline__ float silu_f(float v) {
    return v / (1.0f + __expf(-v));
}

__device__ __forceinline__ unsigned short f2bf(float f) {
    unsigned int u = __float_as_uint(f);
    unsigned int r = (u + 0x7FFFu + ((u >> 16) & 1u)) >> 16;  // RNE
    return (unsigned short)r;
}

// x[i,h] = embed[clip(an[i])]; a[i,h] = b1[h] + x[i,:] @ Wx[:,h]
__global__ __launch_bounds__(H) void k_embed_lin(const int* __restrict__ an,
                                                 const float* __restrict__ embed,
                                                 const float* __restrict__ wx,
                                                 const float* __restrict__ b1,
                                                 float* __restrict__ x,
                                                 float* __restrict__ a) {
    int i = blockIdx.x, h = threadIdx.x;
    __shared__ float xs[H];
    int z = an[i];
    z = min(max(z, 0), 99);
    float xv = embed[z * H + h];
    x[i * H + h] = xv;
    xs[h] = xv;
    __syncthreads();
    float acc = b1[h];
#pragma unroll 8
    for (int k = 0; k < H; k++) acc += xs[k] * wx[k * H + h];
    a[i * H + h] = acc;
}

// MFMA message kernel. Block = one j, 256 threads (4 waves, wave w owns h in [32w,32w+32)).
// msum[j,h] = sum_i valid(i,j) * silu( a[i,h] + F_ij[0:53] @ wfeat[0:53,h] )
// cnt[j]   = #valid i
__global__ __launch_bounds__(256) void k_msg(const float* __restrict__ a,
                                             const float* __restrict__ pos,
                                             const float* __restrict__ wfeat,
                                             float* __restrict__ msum,
                                             int* __restrict__ cnt) {
    int j = blockIdx.x;
    int tid = threadIdx.x;
    int lane = tid & 63;
    int wv = tid >> 6;        // wave 0..3
    int nn = lane & 15;       // tile column
    int quad = lane >> 4;     // 0..3

    __shared__ unsigned short F[SUPER * FSTRIDE];  // bf16 features
    __shared__ float validf[SUPER];
    __shared__ int cnt_sh;

    if (tid == 0) cnt_sh = 0;

    float pjx = pos[j * 3 + 0], pjy = pos[j * 3 + 1], pjz = pos[j * 3 + 2];

    // B fragments: loop-invariant, loaded once. bfrag[kstep][htile]
    // B[k = quad*8+jj (+32*kstep)][n = hbase + 16*htile + nn]
    int hbase = wv * 32;
    short8 bfrag[2][2];
    for (int c = 0; c < 2; c++) {
        for (int t = 0; t < 2; t++) {
            short8 b;
            int h = hbase + 16 * t + nn;
#pragma unroll
            for (int jj = 0; jj < 8; jj++) {
                int k = c * 32 + quad * 8 + jj;
                float v = (k < NUM_RBF + 3) ? wfeat[k * H + h] : 0.0f;
                b[jj] = (short)f2bf(v);
            }
            bfrag[c][t] = b;
        }
    }

    const float DELTA = 5.0f / 49.0f;
    float pacc0 = 0.0f, pacc1 = 0.0f;

    for (int s = 0; s < N / SUPER; s++) {
        __syncthreads();   // protect F/validf from previous iteration's readers
        {
            // stage features: thread t -> i_local = t>>2, k strip = (t&3)*16 .. +16
            int il = tid >> 2;
            int kb = (tid & 3) * 16;
            int i = s * SUPER + il;
            float dx = pos[i * 3 + 0] - pjx;
            float dy = pos[i * 3 + 1] - pjy;
            float dz = pos[i * 3 + 2] - pjz;
            float d = sqrtf(dx * dx + dy * dy + dz * dz);
            float rinv = 1.0f / fmaxf(d, 1e-8f);
            unsigned short vals[16];
#pragma unroll
            for (int q = 0; q < 16; q++) {
                int k = kb + q;
                float v;
                if (k < NUM_RBF) {
                    float tt = d - (float)k * DELTA;
                    v = __expf(-50.0f * tt * tt);      // 1/(2*0.1^2) = 50
                } else if (k == NUM_RBF)     v = dx * rinv;
                else if (k == NUM_RBF + 1)   v = dy * rinv;
                else if (k == NUM_RBF + 2)   v = dz * rinv;
                else                         v = 0.0f;
                vals[q] = f2bf(v);
            }
            unsigned int* dst = (unsigned int*)&F[il * FSTRIDE + kb];
#pragma unroll
            for (int q = 0; q < 8; q++)
                dst[q] = (unsigned int)vals[2 * q] | ((unsigned int)vals[2 * q + 1] << 16);
            int v = (d < 5.0f) && (i != j);
            if ((tid & 3) == 0) validf[il] = (float)v;
            unsigned long long bal = __ballot(((lane & 3) == 0) && v);
            if (lane == 0) atomicAdd(&cnt_sh, __popcll(bal));
        }
        __syncthreads();

#pragma unroll
        for (int it = 0; it < SUPER / 16; it++) {
            // A frags: A[m = lane&15][k = quad*8 + jj (+32c)] from F rows
            short8 afrag0 = *(const short8*)&F[(it * 16 + nn) * FSTRIDE + 0 * 32 + quad * 8];
            short8 afrag1 = *(const short8*)&F[(it * 16 + nn) * FSTRIDE + 1 * 32 + quad * 8];
            // C init = a[i,h]; C/D: col = lane&15, row = quad*4 + reg
            float4v acc0, acc1;
            int ibase = s * SUPER + it * 16 + quad * 4;
#pragma unroll
            for (int r = 0; r < 4; r++) {
                acc0[r] = a[(ibase + r) * H + hbase + nn];
                acc1[r] = a[(ibase + r) * H + hbase + 16 + nn];
            }
            acc0 = __builtin_amdgcn_mfma_f32_16x16x32_bf16(afrag0, bfrag[0][0], acc0, 0, 0, 0);
            acc0 = __builtin_amdgcn_mfma_f32_16x16x32_bf16(afrag1, bfrag[1][0], acc0, 0, 0, 0);
            acc1 = __builtin_amdgcn_mfma_f32_16x16x32_bf16(afrag0, bfrag[0][1], acc1, 0, 0, 0);
            acc1 = __builtin_amdgcn_mfma_f32_16x16x32_bf16(afrag1, bfrag[1][1], acc1, 0, 0, 0);
#pragma unroll
            for (int r = 0; r < 4; r++) {
                float vm = validf[it * 16 + quad * 4 + r];
                pacc0 += vm * silu_f(acc0[r]);
                pacc1 += vm * silu_f(acc1[r]);
            }
        }
    }

    // reduce partials over quads (lanes nn, nn+16, nn+32, nn+48 share a column)
    pacc0 += __shfl_xor(pacc0, 16, 64);
    pacc0 += __shfl_xor(pacc0, 32, 64);
    pacc1 += __shfl_xor(pacc1, 16, 64);
    pacc1 += __shfl_xor(pacc1, 32, 64);
    if (lane < 16) {
        msum[j * H + hbase + nn]      = pacc0;
        msum[j * H + hbase + 16 + nn] = pacc1;
    }
    if (tid == 0) cnt[j] = cnt_sh;
}

// aggr = msum@W2 + cnt*b2; x += silu([x,aggr]@U1 + ub1)@U2 + ub2;
// optionally a_next = b1n + x_new @ Wxn  (fused next-layer input projection)
__global__ __launch_bounds__(H) void k_update(const float* __restrict__ msum,
                                              const int* __restrict__ cnt,
                                              const float* __restrict__ w2,
                                              const float* __restrict__ b2,
                                              const float* __restrict__ u1,
                                              const float* __restrict__ ub1,
                                              const float* __restrict__ u2,
                                              const float* __restrict__ ub2,
                                              float* __restrict__ x,
                                              const float* __restrict__ wxn,
                                              const float* __restrict__ b1n,
                                              float* __restrict__ a_next) {
    int j = blockIdx.x, h = threadIdx.x;
    __shared__ float sj[H];
    __shared__ float xj[H];
    __shared__ float ag[H];
    __shared__ float hid[H];
    __shared__ float xn[H];

    sj[h] = msum[j * H + h];
    xj[h] = x[j * H + h];
    int c = cnt[j];
    __syncthreads();

    float aggr = (float)c * b2[h];
#pragma unroll 8
    for (int k = 0; k < H; k++) aggr += sj[k] * w2[k * H + h];
    ag[h] = aggr;
    __syncthreads();

    float pre = ub1[h];
#pragma unroll 8
    for (int k = 0; k < H; k++) pre += xj[k] * u1[k * H + h];
#pragma unroll 8
    for (int k = 0; k < H; k++) pre += ag[k] * u1[(H + k) * H + h];
    hid[h] = silu_f(pre);
    __syncthreads();

    float o = ub2[h];
#pragma unroll 8
    for (int k = 0; k < H; k++) o += hid[k] * u2[k * H + h];
    float xv = xj[h] + o;
    x[j * H + h] = xv;

    if (a_next != nullptr) {
        xn[h] = xv;
        __syncthreads();
        float acc = b1n[h];
#pragma unroll 8
        for (int k = 0; k < H; k++) acc += xn[k] * wxn[k * H + h];
        a_next[j * H + h] = acc;
    }
}

// per-molecule mean pool + 2-layer output MLP
__global__ __launch_bounds__(H) void k_pool(const float* __restrict__ x,
                                            const int* __restrict__ batch,
                                            const float* __restrict__ ow1,
                                            const float* __restrict__ ob1,
                                            const float* __restrict__ ow2,
                                            const float* __restrict__ ob2,
                                            float* __restrict__ out) {
    int m = blockIdx.x, h = threadIdx.x;
    __shared__ float pooled[H];
    __shared__ float hid[H / 2];

    float s = 0.0f;
    int cntm = 0;
    for (int i = 0; i < N; i++) {
        if (batch[i] == m) { s += x[i * H + h]; cntm++; }
    }
    pooled[h] = s / (float)max(cntm, 1);
    __syncthreads();

    if (h < H / 2) {
        float p = ob1[h];
        for (int k = 0; k < H; k++) p += pooled[k] * ow1[k * (H / 2) + h];
        hid[h] = silu_f(p);
    }
    __syncthreads();

    if (h == 0) {
        float o = ob2[0];
        for (int k = 0; k < H / 2; k++) o += hid[k] * ow2[k];
        out[m] = o;
    }
}

extern "C" void kernel_launch(void* const* d_in, const int* in_sizes, int n_in,
                              void* d_out, int out_size, void* d_ws, size_t ws_size,
                              hipStream_t stream) {
    const int*   an      = (const int*)d_in[0];
    const float* pos     = (const float*)d_in[1];
    const int*   batch   = (const int*)d_in[2];
    const float* embed   = (const float*)d_in[3];
    const float* msg_w1  = (const float*)d_in[4];   // L x 181 x 128
    const float* msg_b1  = (const float*)d_in[5];
    const float* msg_w2  = (const float*)d_in[6];   // L x 128 x 128
    const float* msg_b2  = (const float*)d_in[7];
    const float* upd_w1  = (const float*)d_in[8];   // L x 256 x 128
    const float* upd_b1  = (const float*)d_in[9];
    const float* upd_w2  = (const float*)d_in[10];  // L x 128 x 128
    const float* upd_b2  = (const float*)d_in[11];
    const float* out_w1  = (const float*)d_in[12];  // 128 x 64
    const float* out_b1  = (const float*)d_in[13];
    const float* out_w2  = (const float*)d_in[14];  // 64 x 1
    const float* out_b2  = (const float*)d_in[15];
    float* out = (float*)d_out;

    float* x    = (float*)d_ws;       // N*H
    float* a    = x + N * H;          // N*H
    float* msum = a + N * H;          // N*H
    int*   cnt  = (int*)(msum + N * H);

    const int W1ROWS = H + NUM_RBF + 3;  // 181

    k_embed_lin<<<N, H, 0, stream>>>(an, embed, msg_w1, msg_b1, x, a);
    for (int l = 0; l < L; l++) {
        k_msg<<<N, 256, 0, stream>>>(a, pos, msg_w1 + l * W1ROWS * H + H * H, msum, cnt);
        const float* wxn = (l + 1 < L) ? (msg_w1 + (l + 1) * W1ROWS * H) : nullptr;
        const float* b1n = (l + 1 < L) ? (msg_b1 + (l + 1) * H) : nullptr;
        float* an_ = (l + 1 < L) ? a : nullptr;
        k_update<<<N, H, 0, stream>>>(msum, cnt,
                                      msg_w2 + l * H * H, msg_b2 + l * H,
                                      upd_w1 + l * 2 * H * H, upd_b1 + l * H,
                                      upd_w2 + l * H * H, upd_b2 + l * H, x,
                                      wxn, b1n, an_);
    }
    k_pool<<<NMOL, H, 0, stream>>>(x, batch, out_w1, out_b1, out_w2, out_b2, out);
}

// Round 3
// 295.466 us; speedup vs baseline: 1.7929x; 1.1359x over previous
//
#include <hip/hip_runtime.h>
#include <math.h>

#define N 512
#define H 128
#define L 4
#define NUM_RBF 50
#define NMOL 16
#define SUPER 64          // i's staged per super-tile in k_msg
#define FSTRIDE 72        // bf16 row stride for F_lds (64 + 8 pad)

typedef __attribute__((ext_vector_type(8))) short short8;
typedef __attribute__((ext_vector_type(4))) float float4v;

__device__ __forceinline__ float silu_f(float v) {
    return v / (1.0f + __expf(-v));
}

__device__ __forceinline__ unsigned short f2bf(float f) {
    unsigned int u = __float_as_uint(f);
    unsigned int r = (u + 0x7FFFu + ((u >> 16) & 1u)) >> 16;  // RNE
    return (unsigned short)r;
}

// x[i,h] = embed[clip(an[i])]; a[i,h] = b1[h] + x[i,:] @ Wx[:,h]
__global__ __launch_bounds__(H) void k_embed_lin(const int* __restrict__ an,
                                                 const float* __restrict__ embed,
                                                 const float* __restrict__ wx,
                                                 const float* __restrict__ b1,
                                                 float* __restrict__ x,
                                                 float* __restrict__ a) {
    int i = blockIdx.x, h = threadIdx.x;
    __shared__ float xs[H];
    int z = an[i];
    z = min(max(z, 0), 99);
    float xv = embed[z * H + h];
    x[i * H + h] = xv;
    xs[h] = xv;
    __syncthreads();
    float acc = b1[h];
#pragma unroll 8
    for (int k = 0; k < H; k++) acc += xs[k] * wx[k * H + h];
    a[i * H + h] = acc;
}

// MFMA message kernel. Block = (j, i-half). Grid = 2N. 256 threads (4 waves).
// msum2[half, j, h] = sum_{i in half} valid(i,j) * silu( a[i,h] + F_ij[0:53] @ wfeat[0:53,h] )
__global__ __launch_bounds__(256) void k_msg(const float* __restrict__ a,
                                             const float* __restrict__ pos,
                                             const float* __restrict__ wfeat,
                                             float* __restrict__ msum2,
                                             int* __restrict__ cnt2) {
    int bx = blockIdx.x;
    int j = bx >> 1;
    int half = bx & 1;
    int tid = threadIdx.x;
    int lane = tid & 63;
    int wv = tid >> 6;        // wave 0..3
    int nn = lane & 15;       // tile column
    int quad = lane >> 4;     // 0..3

    __shared__ unsigned short F[SUPER * FSTRIDE];  // bf16 features
    __shared__ float validf[SUPER];
    __shared__ int cnt_sh;

    if (tid == 0) cnt_sh = 0;

    float pjx = pos[j * 3 + 0], pjy = pos[j * 3 + 1], pjz = pos[j * 3 + 2];

    // B fragments: loop-invariant. B[k = 32c + quad*8+jj][n = hbase + 16t + nn]
    int hbase = wv * 32;
    short8 bfrag[2][2];
    for (int c = 0; c < 2; c++) {
        for (int t = 0; t < 2; t++) {
            short8 b;
            int h = hbase + 16 * t + nn;
#pragma unroll
            for (int jj = 0; jj < 8; jj++) {
                int k = c * 32 + quad * 8 + jj;
                float v = (k < NUM_RBF + 3) ? wfeat[k * H + h] : 0.0f;
                b[jj] = (short)f2bf(v);
            }
            bfrag[c][t] = b;
        }
    }

    const float DELTA = 5.0f / 49.0f;
    float pacc0 = 0.0f, pacc1 = 0.0f;

    for (int s = half * (N / SUPER / 2); s < (half + 1) * (N / SUPER / 2); s++) {
        __syncthreads();   // protect F/validf from previous iteration's readers
        {
            // stage features: thread t -> i_local = t>>2, k strip = (t&3)*16 .. +16
            int il = tid >> 2;
            int kb = (tid & 3) * 16;
            int i = s * SUPER + il;
            float dx = pos[i * 3 + 0] - pjx;
            float dy = pos[i * 3 + 1] - pjy;
            float dz = pos[i * 3 + 2] - pjz;
            float d = sqrtf(dx * dx + dy * dy + dz * dz);
            float rinv = 1.0f / fmaxf(d, 1e-8f);
            unsigned short vals[16];
#pragma unroll
            for (int q = 0; q < 16; q++) {
                int k = kb + q;
                float v;
                if (k < NUM_RBF) {
                    float tt = d - (float)k * DELTA;
                    v = __expf(-50.0f * tt * tt);      // 1/(2*0.1^2) = 50
                } else if (k == NUM_RBF)     v = dx * rinv;
                else if (k == NUM_RBF + 1)   v = dy * rinv;
                else if (k == NUM_RBF + 2)   v = dz * rinv;
                else                         v = 0.0f;
                vals[q] = f2bf(v);
            }
            unsigned int* dst = (unsigned int*)&F[il * FSTRIDE + kb];
#pragma unroll
            for (int q = 0; q < 8; q++)
                dst[q] = (unsigned int)vals[2 * q] | ((unsigned int)vals[2 * q + 1] << 16);
            int v = (d < 5.0f) && (i != j);
            if ((tid & 3) == 0) validf[il] = (float)v;
            unsigned long long bal = __ballot(((lane & 3) == 0) && v);
            if (lane == 0) atomicAdd(&cnt_sh, __popcll(bal));
        }
        __syncthreads();

#pragma unroll
        for (int it = 0; it < SUPER / 16; it++) {
            int ibase = s * SUPER + it * 16 + quad * 4;
            // a-values loaded early; consumed only AFTER the MFMAs (epilogue add),
            // so the loads overlap MFMA execution instead of gating it.
            float av0[4], av1[4];
#pragma unroll
            for (int r = 0; r < 4; r++) {
                av0[r] = a[(ibase + r) * H + hbase + nn];
                av1[r] = a[(ibase + r) * H + hbase + 16 + nn];
            }
            // A frags: A[m = lane&15][k = 32c + quad*8 + jj]
            short8 afrag0 = *(const short8*)&F[(it * 16 + nn) * FSTRIDE + 0 * 32 + quad * 8];
            short8 afrag1 = *(const short8*)&F[(it * 16 + nn) * FSTRIDE + 1 * 32 + quad * 8];
            float4v acc0 = {0.0f, 0.0f, 0.0f, 0.0f};
            float4v acc1 = {0.0f, 0.0f, 0.0f, 0.0f};
            acc0 = __builtin_amdgcn_mfma_f32_16x16x32_bf16(afrag0, bfrag[0][0], acc0, 0, 0, 0);
            acc0 = __builtin_amdgcn_mfma_f32_16x16x32_bf16(afrag1, bfrag[1][0], acc0, 0, 0, 0);
            acc1 = __builtin_amdgcn_mfma_f32_16x16x32_bf16(afrag0, bfrag[0][1], acc1, 0, 0, 0);
            acc1 = __builtin_amdgcn_mfma_f32_16x16x32_bf16(afrag1, bfrag[1][1], acc1, 0, 0, 0);
            float4v vm4 = *(const float4v*)&validf[it * 16 + quad * 4];
#pragma unroll
            for (int r = 0; r < 4; r++) {
                pacc0 += vm4[r] * silu_f(acc0[r] + av0[r]);
                pacc1 += vm4[r] * silu_f(acc1[r] + av1[r]);
            }
        }
    }

    // reduce partials over quads (lanes nn, nn+16, nn+32, nn+48 share a column)
    pacc0 += __shfl_xor(pacc0, 16, 64);
    pacc0 += __shfl_xor(pacc0, 32, 64);
    pacc1 += __shfl_xor(pacc1, 16, 64);
    pacc1 += __shfl_xor(pacc1, 32, 64);
    if (lane < 16) {
        msum2[(half * N + j) * H + hbase + nn]      = pacc0;
        msum2[(half * N + j) * H + hbase + 16 + nn] = pacc1;
    }
    if (tid == 0) cnt2[half * N + j] = cnt_sh;
}

// Split-K update: 256 threads = 2 half-groups of 128. Each half computes half of
// every GEMV k-loop; LDS reduce. aggr = msum@W2 + cnt*b2;
// x += silu([x,aggr]@U1 + ub1)@U2 + ub2; optional a_next = b1n + x_new@Wxn.
__global__ __launch_bounds__(256) void k_update(const float* __restrict__ msum2,
                                                const int* __restrict__ cnt2,
                                                const float* __restrict__ w2,
                                                const float* __restrict__ b2,
                                                const float* __restrict__ u1,
                                                const float* __restrict__ ub1,
                                                const float* __restrict__ u2,
                                                const float* __restrict__ ub2,
                                                float* __restrict__ x,
                                                const float* __restrict__ wxn,
                                                const float* __restrict__ b1n,
                                                float* __restrict__ a_next) {
    int j = blockIdx.x;
    int h = threadIdx.x & 127;
    int half = threadIdx.x >> 7;   // 0: waves 0-1, 1: waves 2-3 (wave-uniform)

    __shared__ float sj[H], xj[H], ag[H], hid[H], xn[H];
    __shared__ float part[2][H];

    if (half == 0) {
        sj[h] = msum2[j * H + h] + msum2[(N + j) * H + h];
        xj[h] = x[j * H + h];
    }
    int c = cnt2[j] + cnt2[N + j];
    __syncthreads();

    float p = 0.0f;
#pragma unroll 8
    for (int k = half * 64; k < half * 64 + 64; k++) p += sj[k] * w2[k * H + h];
    part[half][h] = p;
    __syncthreads();
    if (half == 0) ag[h] = part[0][h] + part[1][h] + (float)c * b2[h];
    __syncthreads();

    const float* src = (half == 0) ? xj : ag;
    p = 0.0f;
#pragma unroll 8
    for (int k = 0; k < H; k++) p += src[k] * u1[(half * H + k) * H + h];
    part[half][h] = p;
    __syncthreads();
    if (half == 0) hid[h] = silu_f(part[0][h] + part[1][h] + ub1[h]);
    __syncthreads();

    p = 0.0f;
#pragma unroll 8
    for (int k = half * 64; k < half * 64 + 64; k++) p += hid[k] * u2[k * H + h];
    part[half][h] = p;
    __syncthreads();
    float xv = xj[h] + part[0][h] + part[1][h] + ub2[h];
    if (half == 0) {
        x[j * H + h] = xv;
        xn[h] = xv;
    }

    if (a_next != nullptr) {
        __syncthreads();
        p = 0.0f;
#pragma unroll 8
        for (int k = half * 64; k < half * 64 + 64; k++) p += xn[k] * wxn[k * H + h];
        part[half][h] = p;
        __syncthreads();
        if (half == 0) a_next[j * H + h] = part[0][h] + part[1][h] + b1n[h];
    }
}

// per-molecule mean pool + 2-layer output MLP
__global__ __launch_bounds__(H) void k_pool(const float* __restrict__ x,
                                            const int* __restrict__ batch,
                                            const float* __restrict__ ow1,
                                            const float* __restrict__ ob1,
                                            const float* __restrict__ ow2,
                                            const float* __restrict__ ob2,
                                            float* __restrict__ out) {
    int m = blockIdx.x, h = threadIdx.x;
    __shared__ float pooled[H];
    __shared__ float hid[H / 2];

    float s = 0.0f;
    int cntm = 0;
    for (int i = 0; i < N; i++) {
        if (batch[i] == m) { s += x[i * H + h]; cntm++; }
    }
    pooled[h] = s / (float)max(cntm, 1);
    __syncthreads();

    if (h < H / 2) {
        float p = ob1[h];
        for (int k = 0; k < H; k++) p += pooled[k] * ow1[k * (H / 2) + h];
        hid[h] = silu_f(p);
    }
    __syncthreads();

    if (h == 0) {
        float o = ob2[0];
        for (int k = 0; k < H / 2; k++) o += hid[k] * ow2[k];
        out[m] = o;
    }
}

extern "C" void kernel_launch(void* const* d_in, const int* in_sizes, int n_in,
                              void* d_out, int out_size, void* d_ws, size_t ws_size,
                              hipStream_t stream) {
    const int*   an      = (const int*)d_in[0];
    const float* pos     = (const float*)d_in[1];
    const int*   batch   = (const int*)d_in[2];
    const float* embed   = (const float*)d_in[3];
    const float* msg_w1  = (const float*)d_in[4];   // L x 181 x 128
    const float* msg_b1  = (const float*)d_in[5];
    const float* msg_w2  = (const float*)d_in[6];   // L x 128 x 128
    const float* msg_b2  = (const float*)d_in[7];
    const float* upd_w1  = (const float*)d_in[8];   // L x 256 x 128
    const float* upd_b1  = (const float*)d_in[9];
    const float* upd_w2  = (const float*)d_in[10];  // L x 128 x 128
    const float* upd_b2  = (const float*)d_in[11];
    const float* out_w1  = (const float*)d_in[12];  // 128 x 64
    const float* out_b1  = (const float*)d_in[13];
    const float* out_w2  = (const float*)d_in[14];  // 64 x 1
    const float* out_b2  = (const float*)d_in[15];
    float* out = (float*)d_out;

    float* x     = (float*)d_ws;        // N*H
    float* a     = x + N * H;           // N*H
    float* msum2 = a + N * H;           // 2*N*H
    int*   cnt2  = (int*)(msum2 + 2 * N * H);  // 2*N

    const int W1ROWS = H + NUM_RBF + 3;  // 181

    k_embed_lin<<<N, H, 0, stream>>>(an, embed, msg_w1, msg_b1, x, a);
    for (int l = 0; l < L; l++) {
        k_msg<<<2 * N, 256, 0, stream>>>(a, pos, msg_w1 + l * W1ROWS * H + H * H, msum2, cnt2);
        const float* wxn = (l + 1 < L) ? (msg_w1 + (l + 1) * W1ROWS * H) : nullptr;
        const float* b1n = (l + 1 < L) ? (msg_b1 + (l + 1) * H) : nullptr;
        float* an_ = (l + 1 < L) ? a : nullptr;
        k_update<<<N, 256, 0, stream>>>(msum2, cnt2,
                                        msg_w2 + l * H * H, msg_b2 + l * H,
                                        upd_w1 + l * 2 * H * H, upd_b1 + l * H,
                                        upd_w2 + l * H * H, upd_b2 + l * H, x,
                                        wxn, b1n, an_);
    }
    k_pool<<<NMOL, H, 0, stream>>>(x, batch, out_w1, out_b1, out_w2, out_b2, out);
}

// Round 4
// 259.189 us; speedup vs baseline: 2.0438x; 1.1400x over previous
//
#include <hip/hip_runtime.h>
#include <math.h>

#define N 512
#define H 128
#define L 4
#define NUM_RBF 50
#define NMOL 16
#define SUPER 64          // i's staged per super-tile in k_msg
#define FSTRIDE 72        // bf16 row stride for F_lds (64 + 8 pad)
#define QSPL 4            // i-range splits per j in k_msg

typedef __attribute__((ext_vector_type(8))) short short8;
typedef __attribute__((ext_vector_type(4))) float float4v;

__device__ __forceinline__ float silu_f(float v) {
    return v / (1.0f + __expf(-v));
}

__device__ __forceinline__ unsigned short f2bf(float f) {
    unsigned int u = __float_as_uint(f);
    unsigned int r = (u + 0x7FFFu + ((u >> 16) & 1u)) >> 16;  // RNE
    return (unsigned short)r;
}

// x[i,h] = embed[clip(an[i])]; a[i,h] = b1[h] + x[i,:] @ Wx[:,h]
__global__ __launch_bounds__(H) void k_embed_lin(const int* __restrict__ an,
                                                 const float* __restrict__ embed,
                                                 const float* __restrict__ wx,
                                                 const float* __restrict__ b1,
                                                 float* __restrict__ x,
                                                 float* __restrict__ a) {
    int i = blockIdx.x, h = threadIdx.x;
    __shared__ float xs[H];
    int z = an[i];
    z = min(max(z, 0), 99);
    float xv = embed[z * H + h];
    x[i * H + h] = xv;
    xs[h] = xv;
    __syncthreads();
    float a0 = b1[h], a1 = 0.f, a2 = 0.f, a3 = 0.f;
#pragma unroll 8
    for (int k = 0; k < H; k += 4) {
        a0 += xs[k]     * wx[(k)     * H + h];
        a1 += xs[k + 1] * wx[(k + 1) * H + h];
        a2 += xs[k + 2] * wx[(k + 2) * H + h];
        a3 += xs[k + 3] * wx[(k + 3) * H + h];
    }
    a[i * H + h] = (a0 + a1) + (a2 + a3);
}

// MFMA message kernel. Block = (j, i-quarter). Grid = QSPL*N. 256 threads (4 waves).
// msum4[q, j, h] = sum_{i in quarter q} valid(i,j) * silu( a[i,h] + F_ij[0:53] @ wfeat[0:53,h] )
__global__ __launch_bounds__(256) void k_msg(const float* __restrict__ a,
                                             const float* __restrict__ pos,
                                             const float* __restrict__ wfeat,
                                             float* __restrict__ msum4,
                                             int* __restrict__ cnt4) {
    int bx = blockIdx.x;
    int j = bx >> 2;
    int q = bx & (QSPL - 1);
    int tid = threadIdx.x;
    int lane = tid & 63;
    int wv = tid >> 6;        // wave 0..3
    int nn = lane & 15;       // tile column
    int quad = lane >> 4;     // 0..3

    __shared__ unsigned short F[SUPER * FSTRIDE];  // bf16 features
    __shared__ float validf[SUPER];
    __shared__ int cnt_sh;

    if (tid == 0) cnt_sh = 0;

    float pjx = pos[j * 3 + 0], pjy = pos[j * 3 + 1], pjz = pos[j * 3 + 2];

    // B fragments: loop-invariant. B[k = 32c + quad*8+jj][n = hbase + 16t + nn]
    int hbase = wv * 32;
    short8 bfrag[2][2];
    for (int c = 0; c < 2; c++) {
        for (int t = 0; t < 2; t++) {
            short8 b;
            int h = hbase + 16 * t + nn;
#pragma unroll
            for (int jj = 0; jj < 8; jj++) {
                int k = c * 32 + quad * 8 + jj;
                float v = (k < NUM_RBF + 3) ? wfeat[k * H + h] : 0.0f;
                b[jj] = (short)f2bf(v);
            }
            bfrag[c][t] = b;
        }
    }

    const float DELTA = 5.0f / 49.0f;
    float pacc0 = 0.0f, pacc1 = 0.0f;

    const int SPQ = N / SUPER / QSPL;   // supertiles per quarter (2)
    for (int s = q * SPQ; s < (q + 1) * SPQ; s++) {
        __syncthreads();   // protect F/validf from previous iteration's readers
        {
            // stage features: thread t -> i_local = t>>2, k strip = (t&3)*16 .. +16
            int il = tid >> 2;
            int kb = (tid & 3) * 16;
            int i = s * SUPER + il;
            float dx = pos[i * 3 + 0] - pjx;
            float dy = pos[i * 3 + 1] - pjy;
            float dz = pos[i * 3 + 2] - pjz;
            float d = sqrtf(dx * dx + dy * dy + dz * dz);
            float rinv = 1.0f / fmaxf(d, 1e-8f);
            unsigned short vals[16];
#pragma unroll
            for (int qq = 0; qq < 16; qq++) {
                int k = kb + qq;
                float v;
                if (k < NUM_RBF) {
                    float tt = d - (float)k * DELTA;
                    v = __expf(-50.0f * tt * tt);      // 1/(2*0.1^2) = 50
                } else if (k == NUM_RBF)     v = dx * rinv;
                else if (k == NUM_RBF + 1)   v = dy * rinv;
                else if (k == NUM_RBF + 2)   v = dz * rinv;
                else                         v = 0.0f;
                vals[qq] = f2bf(v);
            }
            unsigned int* dst = (unsigned int*)&F[il * FSTRIDE + kb];
#pragma unroll
            for (int qq = 0; qq < 8; qq++)
                dst[qq] = (unsigned int)vals[2 * qq] | ((unsigned int)vals[2 * qq + 1] << 16);
            int v = (d < 5.0f) && (i != j);
            if ((tid & 3) == 0) validf[il] = (float)v;
            unsigned long long bal = __ballot(((lane & 3) == 0) && v);
            if (lane == 0) atomicAdd(&cnt_sh, __popcll(bal));
        }
        __syncthreads();

#pragma unroll
        for (int it = 0; it < SUPER / 16; it++) {
            int ibase = s * SUPER + it * 16 + quad * 4;
            // a-values loaded early; consumed only AFTER the MFMAs (epilogue add),
            // so the loads overlap MFMA execution instead of gating it.
            float av0[4], av1[4];
#pragma unroll
            for (int r = 0; r < 4; r++) {
                av0[r] = a[(ibase + r) * H + hbase + nn];
                av1[r] = a[(ibase + r) * H + hbase + 16 + nn];
            }
            // A frags: A[m = lane&15][k = 32c + quad*8 + jj]
            short8 afrag0 = *(const short8*)&F[(it * 16 + nn) * FSTRIDE + 0 * 32 + quad * 8];
            short8 afrag1 = *(const short8*)&F[(it * 16 + nn) * FSTRIDE + 1 * 32 + quad * 8];
            float4v acc0 = {0.0f, 0.0f, 0.0f, 0.0f};
            float4v acc1 = {0.0f, 0.0f, 0.0f, 0.0f};
            acc0 = __builtin_amdgcn_mfma_f32_16x16x32_bf16(afrag0, bfrag[0][0], acc0, 0, 0, 0);
            acc0 = __builtin_amdgcn_mfma_f32_16x16x32_bf16(afrag1, bfrag[1][0], acc0, 0, 0, 0);
            acc1 = __builtin_amdgcn_mfma_f32_16x16x32_bf16(afrag0, bfrag[0][1], acc1, 0, 0, 0);
            acc1 = __builtin_amdgcn_mfma_f32_16x16x32_bf16(afrag1, bfrag[1][1], acc1, 0, 0, 0);
            float4v vm4 = *(const float4v*)&validf[it * 16 + quad * 4];
#pragma unroll
            for (int r = 0; r < 4; r++) {
                pacc0 += vm4[r] * silu_f(acc0[r] + av0[r]);
                pacc1 += vm4[r] * silu_f(acc1[r] + av1[r]);
            }
        }
    }

    // reduce partials over quads (lanes nn, nn+16, nn+32, nn+48 share a column)
    pacc0 += __shfl_xor(pacc0, 16, 64);
    pacc0 += __shfl_xor(pacc0, 32, 64);
    pacc1 += __shfl_xor(pacc1, 16, 64);
    pacc1 += __shfl_xor(pacc1, 32, 64);
    if (lane < 16) {
        msum4[(q * N + j) * H + hbase + nn]      = pacc0;
        msum4[(q * N + j) * H + hbase + 16 + nn] = pacc1;
    }
    if (tid == 0) cnt4[q * N + j] = cnt_sh;
}

// 4-way split-K update: 512 threads = 4 groups of 128. Each group computes a
// quarter of every GEMV k-loop with 4 independent accumulators; LDS reduce.
__global__ __launch_bounds__(512) void k_update(const float* __restrict__ msum4,
                                                const int* __restrict__ cnt4,
                                                const float* __restrict__ w2,
                                                const float* __restrict__ b2,
                                                const float* __restrict__ u1,
                                                const float* __restrict__ ub1,
                                                const float* __restrict__ u2,
                                                const float* __restrict__ ub2,
                                                float* __restrict__ x,
                                                const float* __restrict__ wxn,
                                                const float* __restrict__ b1n,
                                                float* __restrict__ a_next) {
    int j = blockIdx.x;
    int h = threadIdx.x & 127;
    int grp = threadIdx.x >> 7;   // 0..3 (wave-pair uniform)

    __shared__ float sj[H], xj[H], ag[H], hid[H], xn[H];
    __shared__ float part[4][H];

    if (grp == 0) {
        xj[h] = x[j * H + h];
    } else if (grp == 1) {
        sj[h] = msum4[j * H + h] + msum4[(N + j) * H + h]
              + msum4[(2 * N + j) * H + h] + msum4[(3 * N + j) * H + h];
    }
    int c = cnt4[j] + cnt4[N + j] + cnt4[2 * N + j] + cnt4[3 * N + j];
    __syncthreads();

    // aggr = sj @ w2 + c*b2   (K=128, 32 per group, 4 accumulators)
    {
        float p0 = 0.f, p1 = 0.f, p2 = 0.f, p3 = 0.f;
        int k0 = grp * 32;
#pragma unroll 8
        for (int k = 0; k < 32; k += 4) {
            p0 += sj[k0 + k]     * w2[(k0 + k)     * H + h];
            p1 += sj[k0 + k + 1] * w2[(k0 + k + 1) * H + h];
            p2 += sj[k0 + k + 2] * w2[(k0 + k + 2) * H + h];
            p3 += sj[k0 + k + 3] * w2[(k0 + k + 3) * H + h];
        }
        part[grp][h] = (p0 + p1) + (p2 + p3);
    }
    __syncthreads();
    if (grp == 0) ag[h] = part[0][h] + part[1][h] + part[2][h] + part[3][h] + (float)c * b2[h];
    __syncthreads();

    // pre = [xj; ag] @ u1 + ub1   (K=256, 64 per group; groups 0-1 read xj, 2-3 read ag)
    {
        const float* src = (grp < 2) ? xj : ag;
        int sbase = (grp & 1) * 64;
        int k0 = grp * 64;
        float p0 = 0.f, p1 = 0.f, p2 = 0.f, p3 = 0.f;
#pragma unroll 8
        for (int k = 0; k < 64; k += 4) {
            p0 += src[sbase + k]     * u1[(k0 + k)     * H + h];
            p1 += src[sbase + k + 1] * u1[(k0 + k + 1) * H + h];
            p2 += src[sbase + k + 2] * u1[(k0 + k + 2) * H + h];
            p3 += src[sbase + k + 3] * u1[(k0 + k + 3) * H + h];
        }
        part[grp][h] = (p0 + p1) + (p2 + p3);
    }
    __syncthreads();
    if (grp == 0) hid[h] = silu_f(part[0][h] + part[1][h] + part[2][h] + part[3][h] + ub1[h]);
    __syncthreads();

    // o = hid @ u2 + ub2; xv = xj + o
    {
        float p0 = 0.f, p1 = 0.f, p2 = 0.f, p3 = 0.f;
        int k0 = grp * 32;
#pragma unroll 8
        for (int k = 0; k < 32; k += 4) {
            p0 += hid[k0 + k]     * u2[(k0 + k)     * H + h];
            p1 += hid[k0 + k + 1] * u2[(k0 + k + 1) * H + h];
            p2 += hid[k0 + k + 2] * u2[(k0 + k + 2) * H + h];
            p3 += hid[k0 + k + 3] * u2[(k0 + k + 3) * H + h];
        }
        part[grp][h] = (p0 + p1) + (p2 + p3);
    }
    __syncthreads();
    if (grp == 0) {
        float xv = xj[h] + part[0][h] + part[1][h] + part[2][h] + part[3][h] + ub2[h];
        x[j * H + h] = xv;
        xn[h] = xv;
    }

    if (a_next != nullptr) {
        __syncthreads();
        float p0 = 0.f, p1 = 0.f, p2 = 0.f, p3 = 0.f;
        int k0 = grp * 32;
#pragma unroll 8
        for (int k = 0; k < 32; k += 4) {
            p0 += xn[k0 + k]     * wxn[(k0 + k)     * H + h];
            p1 += xn[k0 + k + 1] * wxn[(k0 + k + 1) * H + h];
            p2 += xn[k0 + k + 2] * wxn[(k0 + k + 2) * H + h];
            p3 += xn[k0 + k + 3] * wxn[(k0 + k + 3) * H + h];
        }
        part[grp][h] = (p0 + p1) + (p2 + p3);
        __syncthreads();
        if (grp == 0)
            a_next[j * H + h] = part[0][h] + part[1][h] + part[2][h] + part[3][h] + b1n[h];
    }
}

// per-molecule mean pool + 2-layer output MLP. 256 threads = 2 i-halves.
__global__ __launch_bounds__(256) void k_pool(const float* __restrict__ x,
                                              const int* __restrict__ batch,
                                              const float* __restrict__ ow1,
                                              const float* __restrict__ ob1,
                                              const float* __restrict__ ow2,
                                              const float* __restrict__ ob2,
                                              float* __restrict__ out) {
    int m = blockIdx.x;
    int h = threadIdx.x & 127;
    int half = threadIdx.x >> 7;
    __shared__ float sp[2][H];
    __shared__ int cp[2];
    __shared__ float pooled[H];
    __shared__ float hid[H / 2];

    float s = 0.0f;
    int cntm = 0;
    for (int i = half * (N / 2); i < (half + 1) * (N / 2); i++) {
        if (batch[i] == m) { s += x[i * H + h]; cntm++; }
    }
    sp[half][h] = s;
    if (h == 0) cp[half] = cntm;
    __syncthreads();

    if (half == 0) pooled[h] = (sp[0][h] + sp[1][h]) / (float)max(cp[0] + cp[1], 1);
    __syncthreads();

    if (half == 0 && h < H / 2) {
        float p0 = 0.f, p1 = 0.f;
        for (int k = 0; k < H; k += 2) {
            p0 += pooled[k]     * ow1[(k)     * (H / 2) + h];
            p1 += pooled[k + 1] * ow1[(k + 1) * (H / 2) + h];
        }
        hid[h] = silu_f(p0 + p1 + ob1[h]);
    }
    __syncthreads();

    if (threadIdx.x == 0) {
        float o = ob2[0];
        for (int k = 0; k < H / 2; k++) o += hid[k] * ow2[k];
        out[m] = o;
    }
}

extern "C" void kernel_launch(void* const* d_in, const int* in_sizes, int n_in,
                              void* d_out, int out_size, void* d_ws, size_t ws_size,
                              hipStream_t stream) {
    const int*   an      = (const int*)d_in[0];
    const float* pos     = (const float*)d_in[1];
    const int*   batch   = (const int*)d_in[2];
    const float* embed   = (const float*)d_in[3];
    const float* msg_w1  = (const float*)d_in[4];   // L x 181 x 128
    const float* msg_b1  = (const float*)d_in[5];
    const float* msg_w2  = (const float*)d_in[6];   // L x 128 x 128
    const float* msg_b2  = (const float*)d_in[7];
    const float* upd_w1  = (const float*)d_in[8];   // L x 256 x 128
    const float* upd_b1  = (const float*)d_in[9];
    const float* upd_w2  = (const float*)d_in[10];  // L x 128 x 128
    const float* upd_b2  = (const float*)d_in[11];
    const float* out_w1  = (const float*)d_in[12];  // 128 x 64
    const float* out_b1  = (const float*)d_in[13];
    const float* out_w2  = (const float*)d_in[14];  // 64 x 1
    const float* out_b2  = (const float*)d_in[15];
    float* out = (float*)d_out;

    float* x     = (float*)d_ws;        // N*H
    float* a     = x + N * H;           // N*H
    float* msum4 = a + N * H;           // QSPL*N*H
    int*   cnt4  = (int*)(msum4 + QSPL * N * H);  // QSPL*N

    const int W1ROWS = H + NUM_RBF + 3;  // 181

    k_embed_lin<<<N, H, 0, stream>>>(an, embed, msg_w1, msg_b1, x, a);
    for (int l = 0; l < L; l++) {
        k_msg<<<QSPL * N, 256, 0, stream>>>(a, pos, msg_w1 + l * W1ROWS * H + H * H,
                                            msum4, cnt4);
        const float* wxn = (l + 1 < L) ? (msg_w1 + (l + 1) * W1ROWS * H) : nullptr;
        const float* b1n = (l + 1 < L) ? (msg_b1 + (l + 1) * H) : nullptr;
        float* an_ = (l + 1 < L) ? a : nullptr;
        k_update<<<N, 512, 0, stream>>>(msum4, cnt4,
                                        msg_w2 + l * H * H, msg_b2 + l * H,
                                        upd_w1 + l * 2 * H * H, upd_b1 + l * H,
                                        upd_w2 + l * H * H, upd_b2 + l * H, x,
                                        wxn, b1n, an_);
    }
    k_pool<<<NMOL, 256, 0, stream>>>(x, batch, out_w1, out_b1, out_w2, out_b2, out);
}